// Round 7
// baseline (171.369 us; speedup 1.0000x reference)
//
#include <hip/hip_runtime.h>

#define NI 8
#define NF 100
#define NH 40
#define NC 40
#define NM 41
#define BSZ 2048
#define BT 64
#define XPAD 104   // x-tile LDS row stride (floats), zero-padded 100..103
#define MSTR 68    // msxT row stride (floats)

typedef __attribute__((ext_vector_type(8))) short bf16x8;
typedef __attribute__((ext_vector_type(4))) short bf16x4;
typedef __attribute__((ext_vector_type(4))) float f32x4;
typedef __attribute__((ext_vector_type(4))) unsigned int u32x4;
typedef __attribute__((ext_vector_type(2))) unsigned int u32x2;

// Fragment-array extents (per instance-component ic):
//   Wb1m: [nt(3)][k(3)][lane(64)] x16B  -> 576 u32x4   (k=0..2, f 0..95)
//   Wb1t: [nt(3)][lane(64)]       x8B   -> 192 u32x2   (K16 tail, f 96..99, slot quad*4+j)
//   Wb2m: [nt(7)][lane(64)]       x16B  -> 448 u32x4   (kk=0, h 0..31)
//   Wb2t: [nt(7)][lane(64)]       x8B   -> 448 u32x2   (K16 tail, h 32..39, slot quad*4+j)
#define W1M_N 576
#define W1T_N 192
#define W2M_N 448
#define W2T_N 448

__device__ __forceinline__ unsigned short f2bf(float f) {
    unsigned int u = __builtin_bit_cast(unsigned int, f);
    u += 0x7fffu + ((u >> 16) & 1u);
    return (unsigned short)(u >> 16);
}
__device__ __forceinline__ float bf2f(unsigned short s) {
    unsigned int u = ((unsigned int)s) << 16;
    return __builtin_bit_cast(float, u);
}
__device__ __forceinline__ bf16x8 pack8(float4 u, float4 v) {
    u32x4 w;
    w.x = (unsigned int)f2bf(u.x) | ((unsigned int)f2bf(u.y) << 16);
    w.y = (unsigned int)f2bf(u.z) | ((unsigned int)f2bf(u.w) << 16);
    w.z = (unsigned int)f2bf(v.x) | ((unsigned int)f2bf(v.y) << 16);
    w.w = (unsigned int)f2bf(v.z) | ((unsigned int)f2bf(v.w) << 16);
    return __builtin_bit_cast(bf16x8, w);
}
__device__ __forceinline__ bf16x4 pack4(float4 u) {
    u32x2 w;
    w.x = (unsigned int)f2bf(u.x) | ((unsigned int)f2bf(u.y) << 16);
    w.y = (unsigned int)f2bf(u.z) | ((unsigned int)f2bf(u.w) << 16);
    return __builtin_bit_cast(bf16x4, w);
}

// K=16 tail MFMA via the HARNESS-VERIFIED 16x16x32 instruction only.
// Both operands pack logical tail-k t = quad*4+j into physical slot j (j<4)
// of each quad; slots j>=4 are zero on BOTH sides, so sum_t A_t*B_t is exact
// regardless of the internal slot->k mapping. (R15 lesson: the 16x16x16bf16_1k
// builtin's gfx950 layout is NOT verified -- absmax 3e-2. Do not use it.)
__device__ __forceinline__ f32x4 mfma_tail(bf16x4 a, bf16x4 b, f32x4 c) {
    bf16x8 az = {a.x, a.y, a.z, a.w, (short)0, (short)0, (short)0, (short)0};
    bf16x8 bz = {b.x, b.y, b.z, b.w, (short)0, (short)0, (short)0, (short)0};
    return __builtin_amdgcn_mfma_f32_16x16x32_bf16(az, bz, c, 0, 0, 0);
}

// ---------------------------------------------------------------------------
// K1: W_ic = A_ic @ B_ic (fp32), emit bf16 MFMA B-frags. UNCHANGED from R16.
// ---------------------------------------------------------------------------
__global__ __launch_bounds__(512) void build_w_kernel(
    const float* __restrict__ A, const float* __restrict__ Bp,
    unsigned short* __restrict__ Wb1m, unsigned short* __restrict__ Wb1t,
    unsigned short* __restrict__ Wb2m, unsigned short* __restrict__ Wb2t)
{
    __shared__ __align__(16) float As[NF * NM];
    __shared__ __align__(16) float Bs[NM * NH];
    __shared__ __align__(16) float Ws[NF * NH];
    const int ic = blockIdx.x;
    const float* Ap  = A  + (size_t)ic * NF * NM;
    const float* Bpp = Bp + (size_t)ic * NM * NH;
    for (int idx = threadIdx.x; idx < NF * NM; idx += 512) As[idx] = Ap[idx];
    for (int idx = threadIdx.x; idx < NM * NH; idx += 512) Bs[idx] = Bpp[idx];
    __syncthreads();
    for (int idx = threadIdx.x; idx < NF * (NH / 4); idx += 512) {
        const int f  = idx / (NH / 4);
        const int hq = idx % (NH / 4);
        float4 acc = make_float4(0.f, 0.f, 0.f, 0.f);
        #pragma unroll
        for (int m = 0; m < NM; ++m) {
            const float  a = As[f * NM + m];
            const float4 b = *(const float4*)&Bs[m * NH + hq * 4];
            acc.x += a * b.x; acc.y += a * b.y; acc.z += a * b.z; acc.w += a * b.w;
        }
        *(float4*)&Ws[f * NH + hq * 4] = acc;
    }
    __syncthreads();

    // Wb1 main: k=0..2 (f 0..95)
    for (int e = threadIdx.x; e < W1M_N; e += 512) {
        const int nt = e / 192, k = (e / 64) % 3, ln = e & 63;
        const int colx = ln & 15, quad = ln >> 4;
        const int h = nt * 16 + colx;
        unsigned int w[4];
        #pragma unroll
        for (int jj = 0; jj < 4; ++jj) {
            const int f0 = k * 32 + quad * 8 + jj * 2;
            const int f1 = f0 + 1;
            const unsigned int lo = (f0 < NF && h < NH) ? f2bf(Ws[f0 * NH + h]) : 0;
            const unsigned int hi = (f1 < NF && h < NH) ? f2bf(Ws[f1 * NH + h]) : 0;
            w[jj] = lo | (hi << 16);
        }
        ((u32x4*)Wb1m)[(size_t)ic * W1M_N + e] = (u32x4){w[0], w[1], w[2], w[3]};
    }
    // Wb1 tail: K16 slot quad*4+j <-> f = 96 + quad*4 + j (valid: quad 0 only)
    for (int e = threadIdx.x; e < W1T_N; e += 512) {
        const int nt = e >> 6, ln = e & 63;
        const int colx = ln & 15, quad = ln >> 4;
        const int h = nt * 16 + colx;
        unsigned int w[2];
        #pragma unroll
        for (int jj = 0; jj < 2; ++jj) {
            const int f0 = 96 + quad * 4 + jj * 2;
            const int f1 = f0 + 1;
            const unsigned int lo = (f0 < NF && h < NH) ? f2bf(Ws[f0 * NH + h]) : 0;
            const unsigned int hi = (f1 < NF && h < NH) ? f2bf(Ws[f1 * NH + h]) : 0;
            w[jj] = lo | (hi << 16);
        }
        ((u32x2*)Wb1t)[(size_t)ic * W1T_N + e] = (u32x2){w[0], w[1]};
    }
    // Wb2 main: kk=0 (h 0..31)
    for (int e = threadIdx.x; e < W2M_N; e += 512) {
        const int nt = e >> 6, ln = e & 63;
        const int colx = ln & 15, quad = ln >> 4;
        const int f = nt * 16 + colx;
        unsigned int w[4];
        #pragma unroll
        for (int jj = 0; jj < 4; ++jj) {
            const int h0 = quad * 8 + jj * 2;
            const int h1 = h0 + 1;
            const unsigned int lo = (f < NF && h0 < NH) ? f2bf(Ws[f * NH + h0]) : 0;
            const unsigned int hi = (f < NF && h1 < NH) ? f2bf(Ws[f * NH + h1]) : 0;
            w[jj] = lo | (hi << 16);
        }
        ((u32x4*)Wb2m)[(size_t)ic * W2M_N + e] = (u32x4){w[0], w[1], w[2], w[3]};
    }
    // Wb2 tail: K16 slot quad*4+j <-> h = 32 + quad*4 + j (valid: quads 0-1)
    for (int e = threadIdx.x; e < W2T_N; e += 512) {
        const int nt = e >> 6, ln = e & 63;
        const int colx = ln & 15, quad = ln >> 4;
        const int f = nt * 16 + colx;
        unsigned int w[2];
        #pragma unroll
        for (int jj = 0; jj < 2; ++jj) {
            const int h0 = 32 + quad * 4 + jj * 2;
            const int h1 = h0 + 1;
            const unsigned int lo = (f < NF && h0 < NH) ? f2bf(Ws[f * NH + h0]) : 0;
            const unsigned int hi = (f < NF && h1 < NH) ? f2bf(Ws[f * NH + h1]) : 0;
            w[jj] = lo | (hi << 16);
        }
        ((u32x2*)Wb2t)[(size_t)ic * W2T_N + e] = (u32x2){w[0], w[1]};
    }
}

// ---------------------------------------------------------------------------
// Fused MFMA kernel R20 = R19 (verified-correct dataflow: R16 + reg dbuf)
// + amdgpu_waves_per_eu(2,2): R19's counters showed the compiler PINS the
// register budget at 128 VGPR (its occupancy heuristic) and spilled the
// 66-reg double-buffer to scratch (98MB fetch + 238MB write). This kernel
// runs 8 waves / 1 block/CU = 2 waves/EU regardless, so declaring (2,2)
// costs zero occupancy and raises the allocator budget to 256 VGPR; dbuf
// peak ~170-194 fits. c-order unchanged -> bitwise-identical output.
// ---------------------------------------------------------------------------

#define P1_ISSUE(BM, BTl, cvar) do {                                          \
    const u32x4* pm_ = wb1m + (size_t)(cvar) * W1M_N;                         \
    const u32x2* pt_ = wb1t + (size_t)(cvar) * W1T_N;                         \
    _Pragma("unroll")                                                         \
    for (int e_ = 0; e_ < 9; ++e_) BM[e_] = pm_[e_ * 64 + lane];              \
    _Pragma("unroll")                                                         \
    for (int t_ = 0; t_ < 3; ++t_) BTl[t_] = pt_[t_ * 64 + lane];             \
} while (0)

#define P1_COMPUTE(BM, BTl, cvar) do {                                        \
    const int c_ = (cvar);                                                    \
    _Pragma("unroll")                                                         \
    for (int nt = 0; nt < 3; ++nt) {                                          \
        _Pragma("unroll")                                                     \
        for (int mt = 0; mt < 4; ++mt) {                                      \
            f32x4 P = (f32x4){0.f, 0.f, 0.f, 0.f};                            \
            _Pragma("unroll")                                                 \
            for (int k = 0; k < 3; ++k)                                       \
                P = __builtin_amdgcn_mfma_f32_16x16x32_bf16(                  \
                    a1[mt][k], __builtin_bit_cast(bf16x8, BM[nt * 3 + k]),    \
                    P, 0, 0, 0);                                              \
            P = mfma_tail(a1t[mt], __builtin_bit_cast(bf16x4, BTl[nt]), P);   \
            const float4 mv =                                                 \
                *(const float4*)&msxT[c_ * MSTR + mt * 16 + quad * 4];        \
            H[mt][nt][0] += mv.x * P[0];                                      \
            H[mt][nt][1] += mv.y * P[1];                                      \
            H[mt][nt][2] += mv.z * P[2];                                      \
            H[mt][nt][3] += mv.w * P[3];                                      \
        }                                                                     \
    }                                                                         \
} while (0)

#define P2_ISSUE(BM, BTl, ccv) do {                                           \
    const u32x4* pm_ = wb2m + (size_t)(cp + 4 * (ccv)) * W2M_N;               \
    const u32x2* pt_ = wb2t + (size_t)(cp + 4 * (ccv)) * W2T_N;               \
    _Pragma("unroll")                                                         \
    for (int j_ = 0; j_ < 4; ++j_) if (j_ < ne) {                             \
        BM[j_]  = pm_[(nb + j_) * 64 + lane];                                 \
        BTl[j_] = pt_[(nb + j_) * 64 + lane];                                 \
    }                                                                         \
} while (0)

#define P2_COMPUTE(BM, BTl, cvar) do {                                        \
    const int c_ = (cvar);                                                    \
    _Pragma("unroll")                                                         \
    for (int j = 0; j < 4; ++j) if (j < ne) {                                 \
        _Pragma("unroll")                                                     \
        for (int mt = 0; mt < 4; ++mt) {                                      \
            f32x4 P = (f32x4){0.f, 0.f, 0.f, 0.f};                            \
            P = __builtin_amdgcn_mfma_f32_16x16x32_bf16(                      \
                a2[mt], __builtin_bit_cast(bf16x8, BM[j]), P, 0, 0, 0);       \
            P = mfma_tail(a2t[mt], __builtin_bit_cast(bf16x4, BTl[j]), P);    \
            const float4 mv =                                                 \
                *(const float4*)&msxT[c_ * MSTR + mt * 16 + quad * 4];        \
            Ot[mt][j][0] += mv.x * P[0];                                      \
            Ot[mt][j][1] += mv.y * P[1];                                      \
            Ot[mt][j][2] += mv.z * P[2];                                      \
            Ot[mt][j][3] += mv.w * P[3];                                      \
        }                                                                     \
    }                                                                         \
} while (0)

__global__ __launch_bounds__(512)
__attribute__((amdgpu_waves_per_eu(2, 2)))
void fused_kernel(
    const float* __restrict__ x, const float* __restrict__ mask,
    const float* __restrict__ b_final,
    const unsigned short* __restrict__ Wb1m, const unsigned short* __restrict__ Wb1t,
    const unsigned short* __restrict__ Wb2m, const unsigned short* __restrict__ Wb2t,
    float* __restrict__ out)
{
    __shared__ __align__(16) float msxT[NC * MSTR];          // 10880 B, [c][b]
    __shared__ __align__(16) unsigned char regionB[57344];   // union:
    // phase A: xs[b(64)][XPAD(104)] fp32 (26624 B)
    // phase B: hsP[g(8)][b(64)][h(48)] bf16 (49152 B)
    // phase C: outP[cp(4)][b(64)][f(112)] bf16 (57344 B)
    unsigned short* region = (unsigned short*)regionB;
    float* xs = (float*)regionB;

    const int tid  = threadIdx.x;
    const int lane = tid & 63;
    const int wav  = tid >> 6;       // 0..7
    const int col  = lane & 15;
    const int quad = lane >> 4;
    const int i    = blockIdx.x % NI;
    const int b0   = (blockIdx.x / NI) * BT;

    const u32x4* wb1m = (const u32x4*)Wb1m + (size_t)i * NC * W1M_N;
    const u32x2* wb1t = (const u32x2*)Wb1t + (size_t)i * NC * W1T_N;
    const u32x4* wb2m = (const u32x4*)Wb2m + (size_t)i * NC * W2M_N;
    const u32x2* wb2t = (const u32x2*)Wb2t + (size_t)i * NC * W2T_N;

    // ---- issue pass1 first TWO B-frag sets (c = wav, wav+8) up front ----
    u32x4 bAm0[9], bAm1[9];
    u32x2 bAt0[3], bAt1[3];
    P1_ISSUE(bAm0, bAt0, wav);
    P1_ISSUE(bAm1, bAt1, wav + 8);

    // ---- stage mask (fp32, transposed) + x tile (coalesced float4) ----
    for (int idx = tid; idx < BT * NC; idx += 512) {
        const int b = idx / NC, c = idx % NC;     // coalesced global read
        msxT[c * MSTR + b] = mask[((size_t)(b0 + b) * NI + i) * NC + c];
    }
    for (int idx = tid; idx < BT * (XPAD / 4); idx += 512) {
        const int row = idx / (XPAD / 4), fq = idx % (XPAD / 4);
        float4 v = make_float4(0.f, 0.f, 0.f, 0.f);
        if (fq < NF / 4)
            v = *(const float4*)(x + ((size_t)(b0 + row) * NI + i) * NF + fq * 4);
        *(float4*)&xs[row * XPAD + fq * 4] = v;
    }
    __syncthreads();

    // ---- build X A-fragments from LDS: a1[mt][k] (K 0..95) + K16 tail ----
    bf16x8 a1[4][3];
    bf16x4 a1t[4];
    #pragma unroll
    for (int mt = 0; mt < 4; ++mt) {
        const float* xr = xs + (mt * 16 + col) * XPAD;
        #pragma unroll
        for (int k = 0; k < 3; ++k)
            a1[mt][k] = pack8(*(const float4*)(xr + k * 32 + quad * 8),
                              *(const float4*)(xr + k * 32 + quad * 8 + 4));
        // tail slot quad*4+j <-> f = 96+quad*4+j; quad0: f96-99 (data),
        // quad1: f100-103 (zero-pad cols), quads 2-3: forced zero (stay in-row)
        if (quad < 2)
            a1t[mt] = pack4(*(const float4*)(xr + 96 + quad * 4));
        else
            a1t[mt] = __builtin_bit_cast(bf16x4, (u32x2){0, 0});
    }
    __syncthreads();  // all waves done reading xs before hsP overwrites region

    // ---- pass 1: H[mt][nt] accumulators (M=64, N=48); wave's c = wav+8k ----
    // Straight-line 5 compute blocks, A/B ping-pong, issue distance = 1 block.
    f32x4 H[4][3];
    #pragma unroll
    for (int mt = 0; mt < 4; ++mt)
        #pragma unroll
        for (int nt = 0; nt < 3; ++nt)
            H[mt][nt] = (f32x4){0.f, 0.f, 0.f, 0.f};

    P1_COMPUTE(bAm0, bAt0, wav);
    P1_ISSUE  (bAm0, bAt0, wav + 16);
    P1_COMPUTE(bAm1, bAt1, wav + 8);
    P1_ISSUE  (bAm1, bAt1, wav + 24);
    P1_COMPUTE(bAm0, bAt0, wav + 16);
    P1_ISSUE  (bAm0, bAt0, wav + 32);
    P1_COMPUTE(bAm1, bAt1, wav + 24);
    P1_COMPUTE(bAm0, bAt0, wav + 32);

    // ---- pass2 ownership: fh = nt-range (0:nt0-3, 1:nt4-6), cp = c-phase ----
    const int fh  = wav >> 2;        // 0,1
    const int cp  = wav & 3;         // 0..3; wave's c = cp + 4*cc (10 c's)
    const int ne  = fh ? 3 : 4;      // nt tiles this wave
    const int nb  = fh * 4;          // nt base

    // ---- issue pass2 first TWO B-frag sets (cc = 0, 1) before LDS phases ----
    u32x4 b2m0[4], b2m1[4];
    u32x2 b2t0[4], b2t1[4];
    #pragma unroll
    for (int j = 0; j < 4; ++j) {
        b2m0[j] = (u32x4){0, 0, 0, 0};  b2m1[j] = (u32x4){0, 0, 0, 0};
        b2t0[j] = (u32x2){0, 0};        b2t1[j] = (u32x2){0, 0};
    }
    P2_ISSUE(b2m0, b2t0, 0);
    P2_ISSUE(b2m1, b2t1, 1);

    // ---- write per-wave H partials (bf16): hsP[wav][b][h] ----
    #pragma unroll
    for (int mt = 0; mt < 4; ++mt)
        #pragma unroll
        for (int nt = 0; nt < 3; ++nt)
            #pragma unroll
            for (int r = 0; r < 4; ++r) {
                const int b = mt * 16 + quad * 4 + r;
                const int h = nt * 16 + col;
                region[(wav * 64 + b) * 48 + h] = f2bf(H[mt][nt][r]);
            }
    __syncthreads();

    // ---- 8-way reduce into slot 0, VECTORIZED: thread = (b, 8-h group) ----
    for (int idx = tid; idx < BT * 6; idx += 512) {
        const int b = idx / 6, hq = idx % 6;
        if (hq == 5) {   // h=40..47 pad columns -> zero
            *(u32x4*)&region[b * 48 + 40] = (u32x4){0, 0, 0, 0};
        } else {
            float s[8] = {0.f, 0.f, 0.f, 0.f, 0.f, 0.f, 0.f, 0.f};
            #pragma unroll
            for (int g = 0; g < 8; ++g) {
                const u32x4 v = *(const u32x4*)&region[(g * 64 + b) * 48 + hq * 8];
                const unsigned int vv[4] = {v.x, v.y, v.z, v.w};
                #pragma unroll
                for (int q = 0; q < 4; ++q) {
                    s[q * 2 + 0] += bf2f((unsigned short)(vv[q] & 0xffffu));
                    s[q * 2 + 1] += bf2f((unsigned short)(vv[q] >> 16));
                }
            }
            u32x4 o;
            o.x = (unsigned int)f2bf(s[0]) | ((unsigned int)f2bf(s[1]) << 16);
            o.y = (unsigned int)f2bf(s[2]) | ((unsigned int)f2bf(s[3]) << 16);
            o.z = (unsigned int)f2bf(s[4]) | ((unsigned int)f2bf(s[5]) << 16);
            o.w = (unsigned int)f2bf(s[6]) | ((unsigned int)f2bf(s[7]) << 16);
            *(u32x4*)&region[b * 48 + hq * 8] = o;
        }
    }
    __syncthreads();

    // ---- pass2 A-frags for ALL 4 mt: main (h 0..31) + K16 tail (h 32..47) ----
    bf16x8 a2[4];
    bf16x4 a2t[4];
    #pragma unroll
    for (int mt = 0; mt < 4; ++mt) {
        const int b = mt * 16 + col;
        a2[mt]  = *(const bf16x8*)&region[b * 48 + quad * 8];
        a2t[mt] = *(const bf16x4*)&region[b * 48 + 32 + quad * 4];  // h40-47 = zeros
    }
    __syncthreads();  // everyone done reading hsP before outP overwrites region

    // ---- pass 2: Ot[mt][j]; 10 c's per wave, A/B ping-pong, 2 c's/iter ----
    f32x4 Ot[4][4];
    #pragma unroll
    for (int mt = 0; mt < 4; ++mt)
        #pragma unroll
        for (int j = 0; j < 4; ++j)
            Ot[mt][j] = (f32x4){0.f, 0.f, 0.f, 0.f};

    #pragma unroll 1
    for (int p = 0; p < 5; ++p) {
        P2_COMPUTE(b2m0, b2t0, cp + 8 * p);          // cc = 2p
        if (p < 4) P2_ISSUE(b2m0, b2t0, 2 * p + 2);
        P2_COMPUTE(b2m1, b2t1, cp + 8 * p + 4);      // cc = 2p+1
        if (p < 4) P2_ISSUE(b2m1, b2t1, 2 * p + 3);
    }

    // ---- write out partials (bf16): outP[cp][b][f] ----
    #pragma unroll
    for (int mt = 0; mt < 4; ++mt)
        #pragma unroll
        for (int j = 0; j < 4; ++j) {
            if (j < ne) {
                const int f = (nb + j) * 16 + col;
                if (f < NF) {
                    #pragma unroll
                    for (int r = 0; r < 4; ++r) {
                        const int b = mt * 16 + quad * 4 + r;
                        region[(cp * 64 + b) * 112 + f] = f2bf(Ot[mt][j][r]);
                    }
                }
            }
        }
    __syncthreads();

    // ---- final reduce + bias + relu, VECTORIZED: thread = (b, 8-f group) ----
    for (int idx = tid; idx < BT * 13; idx += 512) {
        const int b = idx / 13, fg = idx % 13;
        const int f0 = fg * 8;
        float s[8] = {0.f, 0.f, 0.f, 0.f, 0.f, 0.f, 0.f, 0.f};
        #pragma unroll
        for (int p = 0; p < 4; ++p) {
            const u32x4 v = *(const u32x4*)&region[(p * 64 + b) * 112 + f0];
            const unsigned int vv[4] = {v.x, v.y, v.z, v.w};
            #pragma unroll
            for (int q = 0; q < 4; ++q) {
                s[q * 2 + 0] += bf2f((unsigned short)(vv[q] & 0xffffu));
                s[q * 2 + 1] += bf2f((unsigned short)(vv[q] >> 16));
            }
        }
        const float* bfp = b_final + i * NF + f0;
        float* op = out + ((size_t)(b0 + b) * NI + i) * NF + f0;
        const float4 bias0 = *(const float4*)bfp;   // f0..f0+3 (<=99 always)
        float4 o0;
        o0.x = fmaxf(s[0] + bias0.x, 0.f);
        o0.y = fmaxf(s[1] + bias0.y, 0.f);
        o0.z = fmaxf(s[2] + bias0.z, 0.f);
        o0.w = fmaxf(s[3] + bias0.w, 0.f);
        *(float4*)op = o0;
        if (fg < 12) {                              // f0+4..f0+7 < 100
            const float4 bias1 = *(const float4*)(bfp + 4);
            float4 o1;
            o1.x = fmaxf(s[4] + bias1.x, 0.f);
            o1.y = fmaxf(s[5] + bias1.y, 0.f);
            o1.z = fmaxf(s[6] + bias1.z, 0.f);
            o1.w = fmaxf(s[7] + bias1.w, 0.f);
            *(float4*)(op + 4) = o1;
        }
    }
}

extern "C" void kernel_launch(void* const* d_in, const int* in_sizes, int n_in,
                              void* d_out, int out_size, void* d_ws, size_t ws_size,
                              hipStream_t stream) {
    const float* x       = (const float*)d_in[0];  // (2048, 8, 100)
    const float* tk_mask = (const float*)d_in[1];  // (2048, 8, 40)
    const float* A       = (const float*)d_in[2];  // (8, 40, 100, 41)
    const float* Bp      = (const float*)d_in[3];  // (8, 40, 41, 40)
    const float* b_final = (const float*)d_in[4];  // (8, 100)
    float* out = (float*)d_out;                    // (2048, 8, 100)

    unsigned char* ws = (unsigned char*)d_ws;
    unsigned short* Wb1m = (unsigned short*)(ws);
    unsigned short* Wb1t = (unsigned short*)(ws + (size_t)NI * NC * W1M_N * 16);
    unsigned short* Wb2m = (unsigned short*)(ws + (size_t)NI * NC * (W1M_N * 16 + W1T_N * 8));
    unsigned short* Wb2t = (unsigned short*)(ws + (size_t)NI * NC * (W1M_N * 16 + W1T_N * 8 + W2M_N * 16));

    build_w_kernel<<<NI * NC, 512, 0, stream>>>(A, Bp, Wb1m, Wb1t, Wb2m, Wb2t);
    fused_kernel<<<(BSZ / BT) * NI, 512, 0, stream>>>(x, tk_mask, b_final,
                                                      Wb1m, Wb1t, Wb2m, Wb2t, out);
}

// Round 8
// 103.736 us; speedup vs baseline: 1.6520x; 1.6520x over previous
//
#include <hip/hip_runtime.h>

#define NI 8
#define NF 100
#define NH 40
#define NC 40
#define NM 41
#define BSZ 2048
#define BT 64
#define XPAD 104   // x-tile LDS row stride (floats), zero-padded 100..103
#define MSTR 68    // msxT row stride (floats)

typedef __attribute__((ext_vector_type(8))) short bf16x8;
typedef __attribute__((ext_vector_type(4))) float f32x4;
typedef __attribute__((ext_vector_type(4))) unsigned int u32x4;

__device__ __forceinline__ unsigned short f2bf(float f) {
    unsigned int u = __builtin_bit_cast(unsigned int, f);
    u += 0x7fffu + ((u >> 16) & 1u);
    return (unsigned short)(u >> 16);
}
__device__ __forceinline__ float bf2f(unsigned short s) {
    unsigned int u = ((unsigned int)s) << 16;
    return __builtin_bit_cast(float, u);
}
__device__ __forceinline__ bf16x8 pack8(float4 u, float4 v) {
    u32x4 w;
    w.x = (unsigned int)f2bf(u.x) | ((unsigned int)f2bf(u.y) << 16);
    w.y = (unsigned int)f2bf(u.z) | ((unsigned int)f2bf(u.w) << 16);
    w.z = (unsigned int)f2bf(v.x) | ((unsigned int)f2bf(v.y) << 16);
    w.w = (unsigned int)f2bf(v.z) | ((unsigned int)f2bf(v.w) << 16);
    return __builtin_bit_cast(bf16x8, w);
}

// ---------------------------------------------------------------------------
// K1: W_ic = A_ic @ B_ic (fp32), emit bf16 MFMA B-frags (layouts verified R2-R13).
//   Wb1: [ic][nt(3)][k(4)][lane(64)] x16B; n=nt*16+(lane&15), f=k*32+(lane>>4)*8+j
//   Wb2: [ic][nt(7)][kk(2)][lane(64)] x16B; n=nt*16+(lane&15), h=kk*32+(lane>>4)*8+j
// ---------------------------------------------------------------------------
__global__ __launch_bounds__(512) void build_w_kernel(
    const float* __restrict__ A, const float* __restrict__ Bp,
    unsigned short* __restrict__ Wb1, unsigned short* __restrict__ Wb2)
{
    __shared__ __align__(16) float As[NF * NM];
    __shared__ __align__(16) float Bs[NM * NH];
    __shared__ __align__(16) float Ws[NF * NH];
    const int ic = blockIdx.x;
    const float* Ap  = A  + (size_t)ic * NF * NM;
    const float* Bpp = Bp + (size_t)ic * NM * NH;
    for (int idx = threadIdx.x; idx < NF * NM; idx += 512) As[idx] = Ap[idx];
    for (int idx = threadIdx.x; idx < NM * NH; idx += 512) Bs[idx] = Bpp[idx];
    __syncthreads();
    for (int idx = threadIdx.x; idx < NF * (NH / 4); idx += 512) {
        const int f  = idx / (NH / 4);
        const int hq = idx % (NH / 4);
        float4 acc = make_float4(0.f, 0.f, 0.f, 0.f);
        #pragma unroll
        for (int m = 0; m < NM; ++m) {
            const float  a = As[f * NM + m];
            const float4 b = *(const float4*)&Bs[m * NH + hq * 4];
            acc.x += a * b.x; acc.y += a * b.y; acc.z += a * b.z; acc.w += a * b.w;
        }
        *(float4*)&Ws[f * NH + hq * 4] = acc;
    }
    __syncthreads();

    for (int e = threadIdx.x; e < 768; e += 512) {
        const int nt = e >> 8, k = (e >> 6) & 3, ln = e & 63;
        const int colx = ln & 15, quad = ln >> 4;
        const int h = nt * 16 + colx;
        unsigned int w[4];
        #pragma unroll
        for (int jj = 0; jj < 4; ++jj) {
            const int f0 = k * 32 + quad * 8 + jj * 2;
            const int f1 = f0 + 1;
            const unsigned int lo = (f0 < NF && h < NH) ? f2bf(Ws[f0 * NH + h]) : 0;
            const unsigned int hi = (f1 < NF && h < NH) ? f2bf(Ws[f1 * NH + h]) : 0;
            w[jj] = lo | (hi << 16);
        }
        ((u32x4*)Wb1)[(size_t)ic * 768 + e] = (u32x4){w[0], w[1], w[2], w[3]};
    }
    for (int e = threadIdx.x; e < 896; e += 512) {
        const int nt = e >> 7, kk = (e >> 6) & 1, ln = e & 63;
        const int colx = ln & 15, quad = ln >> 4;
        const int f = nt * 16 + colx;
        unsigned int w[4];
        #pragma unroll
        for (int jj = 0; jj < 4; ++jj) {
            const int h0 = kk * 32 + quad * 8 + jj * 2;
            const int h1 = h0 + 1;
            const unsigned int lo = (f < NF && h0 < NH) ? f2bf(Ws[f * NH + h0]) : 0;
            const unsigned int hi = (f < NF && h1 < NH) ? f2bf(Ws[f * NH + h1]) : 0;
            w[jj] = lo | (hi << 16);
        }
        ((u32x4*)Wb2)[(size_t)ic * 896 + e] = (u32x4){w[0], w[1], w[2], w[3]};
    }
}

// ---------------------------------------------------------------------------
// Fused MFMA kernel v8 = R10 (verified best, 104.7us) with both reduce phases
// + epilogue vectorized (b128 LDS group reads, float4 stores). Restored
// verbatim after R14-R20 structural experiments were all measured-blocked:
// occupancy (spill/LDS/traffic tri-lemma), W-traffic cut (latency-tolerant,
// neutral), register prefetch (allocator pins 128 VGPR via every control
// surface), barrier/bank/setprio micro-opts (negative in lockstep structure).
// ---------------------------------------------------------------------------
__global__ __launch_bounds__(512, 1) void fused_kernel(
    const float* __restrict__ x, const float* __restrict__ mask,
    const float* __restrict__ b_final,
    const unsigned short* __restrict__ Wb1, const unsigned short* __restrict__ Wb2,
    float* __restrict__ out)
{
    __shared__ __align__(16) float msxT[NC * MSTR];          // 10880 B, [c][b]
    __shared__ __align__(16) unsigned char regionB[57344];   // union:
    // phase A: xs[b(64)][XPAD(104)] fp32 (26624 B)
    // phase B: hsP[g(8)][b(64)][h(48)] bf16 (49152 B)
    // phase C: outP[cp(4)][b(64)][f(112)] bf16 (57344 B)
    unsigned short* region = (unsigned short*)regionB;
    float* xs = (float*)regionB;

    const int tid  = threadIdx.x;
    const int lane = tid & 63;
    const int wav  = tid >> 6;       // 0..7
    const int col  = lane & 15;
    const int quad = lane >> 4;
    const int i    = blockIdx.x % NI;
    const int b0   = (blockIdx.x / NI) * BT;

    const u32x4* wb1i = (const u32x4*)Wb1 + (size_t)i * NC * 768;
    const u32x4* wb2i = (const u32x4*)Wb2 + (size_t)i * NC * 896;

    // ---- issue pass1 first B-frag load (c = wav) before anything else ----
    u32x4 bufA[12];
    {
        const u32x4* p = wb1i + (size_t)wav * 768;
        #pragma unroll
        for (int e = 0; e < 12; ++e) bufA[e] = p[e * 64 + lane];
    }

    // ---- stage mask (fp32, transposed) + x tile (coalesced float4) ----
    for (int idx = tid; idx < BT * NC; idx += 512) {
        const int b = idx / NC, c = idx % NC;     // coalesced global read
        msxT[c * MSTR + b] = mask[((size_t)(b0 + b) * NI + i) * NC + c];
    }
    for (int idx = tid; idx < BT * (XPAD / 4); idx += 512) {
        const int row = idx / (XPAD / 4), fq = idx % (XPAD / 4);
        float4 v = make_float4(0.f, 0.f, 0.f, 0.f);
        if (fq < NF / 4)
            v = *(const float4*)(x + ((size_t)(b0 + row) * NI + i) * NF + fq * 4);
        *(float4*)&xs[row * XPAD + fq * 4] = v;
    }
    __syncthreads();

    // ---- build X A-fragments from LDS: a1[mt][k], M=64, K=128(pad) ----
    bf16x8 a1[4][4];
    #pragma unroll
    for (int mt = 0; mt < 4; ++mt) {
        const float* xr = xs + (mt * 16 + col) * XPAD;
        #pragma unroll
        for (int k = 0; k < 4; ++k) {
            if (k < 3 || quad == 0)
                a1[mt][k] = pack8(*(const float4*)(xr + k * 32 + quad * 8),
                                  *(const float4*)(xr + k * 32 + quad * 8 + 4));
            else
                a1[mt][k] = __builtin_bit_cast(bf16x8, (u32x4){0, 0, 0, 0});
        }
    }
    __syncthreads();  // all waves done reading xs before hsP overwrites region

    // ---- pass 1: H[mt][nt] accumulators (M=64, N=48); wave's c = wav+8k ----
    f32x4 H[4][3];
    #pragma unroll
    for (int mt = 0; mt < 4; ++mt)
        #pragma unroll
        for (int nt = 0; nt < 3; ++nt)
            H[mt][nt] = (f32x4){0.f, 0.f, 0.f, 0.f};

    #pragma unroll 1
    for (int cc = 0; cc < NC / 8; ++cc) {
        const int c = wav + cc * 8;
        #pragma unroll
        for (int nt = 0; nt < 3; ++nt) {
            #pragma unroll
            for (int mt = 0; mt < 4; ++mt) {
                f32x4 P = (f32x4){0.f, 0.f, 0.f, 0.f};
                #pragma unroll
                for (int k = 0; k < 4; ++k)
                    P = __builtin_amdgcn_mfma_f32_16x16x32_bf16(
                        a1[mt][k], __builtin_bit_cast(bf16x8, bufA[nt * 4 + k]), P, 0, 0, 0);
                const float4 mv = *(const float4*)&msxT[c * MSTR + mt * 16 + quad * 4];
                H[mt][nt][0] += mv.x * P[0];
                H[mt][nt][1] += mv.y * P[1];
                H[mt][nt][2] += mv.z * P[2];
                H[mt][nt][3] += mv.w * P[3];
            }
            // nt-group fully consumed -> reload same slots with next c's frags
            if (cc < NC / 8 - 1) {
                const u32x4* p = wb1i + (size_t)(c + 8) * 768;
                #pragma unroll
                for (int k = 0; k < 4; ++k)
                    bufA[nt * 4 + k] = p[(nt * 4 + k) * 64 + lane];
            }
        }
    }

    // ---- pass2 ownership: fh = nt-range (0:nt0-3, 1:nt4-6), cp = c-phase ----
    const int fh  = wav >> 2;        // 0,1
    const int cp  = wav & 3;         // 0..3; wave's c = cp + 4*cc (10 c's)
    const int ne  = fh ? 3 : 4;      // nt tiles this wave
    const int nb  = fh * 4;          // nt base

    // ---- issue pass2 first B-frag load (c = cp) before LDS phases ----
    u32x4 buf2A[8];
    {
        const u32x4* p = wb2i + (size_t)cp * 896;
        #pragma unroll
        for (int j = 0; j < 4; ++j) {
            #pragma unroll
            for (int kk = 0; kk < 2; ++kk) {
                buf2A[j * 2 + kk] = (u32x4){0, 0, 0, 0};
                if (j < ne)
                    buf2A[j * 2 + kk] = p[((nb + j) * 2 + kk) * 64 + lane];
            }
        }
    }

    // ---- write per-wave H partials (bf16): hsP[wav][b][h] ----
    #pragma unroll
    for (int mt = 0; mt < 4; ++mt)
        #pragma unroll
        for (int nt = 0; nt < 3; ++nt)
            #pragma unroll
            for (int r = 0; r < 4; ++r) {
                const int b = mt * 16 + quad * 4 + r;
                const int h = nt * 16 + col;
                region[(wav * 64 + b) * 48 + h] = f2bf(H[mt][nt][r]);
            }
    __syncthreads();

    // ---- 8-way reduce into slot 0, VECTORIZED: thread = (b, 8-h group) ----
    // 64 b x 6 groups = 384 items; 8x ds_read_b128 each, conflict-free.
    for (int idx = tid; idx < BT * 6; idx += 512) {
        const int b = idx / 6, hq = idx % 6;
        if (hq == 5) {   // h=40..47 pad columns -> zero
            *(u32x4*)&region[b * 48 + 40] = (u32x4){0, 0, 0, 0};
        } else {
            float s[8] = {0.f, 0.f, 0.f, 0.f, 0.f, 0.f, 0.f, 0.f};
            #pragma unroll
            for (int g = 0; g < 8; ++g) {
                const u32x4 v = *(const u32x4*)&region[(g * 64 + b) * 48 + hq * 8];
                const unsigned int vv[4] = {v.x, v.y, v.z, v.w};
                #pragma unroll
                for (int q = 0; q < 4; ++q) {
                    s[q * 2 + 0] += bf2f((unsigned short)(vv[q] & 0xffffu));
                    s[q * 2 + 1] += bf2f((unsigned short)(vv[q] >> 16));
                }
            }
            u32x4 o;
            o.x = (unsigned int)f2bf(s[0]) | ((unsigned int)f2bf(s[1]) << 16);
            o.y = (unsigned int)f2bf(s[2]) | ((unsigned int)f2bf(s[3]) << 16);
            o.z = (unsigned int)f2bf(s[4]) | ((unsigned int)f2bf(s[5]) << 16);
            o.w = (unsigned int)f2bf(s[6]) | ((unsigned int)f2bf(s[7]) << 16);
            *(u32x4*)&region[b * 48 + hq * 8] = o;
        }
    }
    __syncthreads();

    // ---- pass2 A-frags for ALL 4 mt (K=40 pad 64) ----
    bf16x8 a2[4][2];
    #pragma unroll
    for (int mt = 0; mt < 4; ++mt) {
        const int b = mt * 16 + col;
        #pragma unroll
        for (int kk = 0; kk < 2; ++kk)
            a2[mt][kk] = *(const bf16x8*)&region[b * 48 + kk * 32 + quad * 8];
    }
    __syncthreads();  // everyone done reading hsP before outP overwrites region

    // ---- pass 2: Ot[mt][j]; 10 c's per wave, depth-1 in-place reload ----
    f32x4 Ot[4][4];
    #pragma unroll
    for (int mt = 0; mt < 4; ++mt)
        #pragma unroll
        for (int j = 0; j < 4; ++j)
            Ot[mt][j] = (f32x4){0.f, 0.f, 0.f, 0.f};

    #pragma unroll 1
    for (int cc = 0; cc < NC / 4; ++cc) {
        const int c = cp + cc * 4;
        #pragma unroll
        for (int j = 0; j < 4; ++j) {
            if (j < ne) {
                #pragma unroll
                for (int mt = 0; mt < 4; ++mt) {
                    f32x4 P = (f32x4){0.f, 0.f, 0.f, 0.f};
                    P = __builtin_amdgcn_mfma_f32_16x16x32_bf16(
                        a2[mt][0], __builtin_bit_cast(bf16x8, buf2A[j * 2 + 0]), P, 0, 0, 0);
                    P = __builtin_amdgcn_mfma_f32_16x16x32_bf16(
                        a2[mt][1], __builtin_bit_cast(bf16x8, buf2A[j * 2 + 1]), P, 0, 0, 0);
                    const float4 mv = *(const float4*)&msxT[c * MSTR + mt * 16 + quad * 4];
                    Ot[mt][j][0] += mv.x * P[0];
                    Ot[mt][j][1] += mv.y * P[1];
                    Ot[mt][j][2] += mv.z * P[2];
                    Ot[mt][j][3] += mv.w * P[3];
                }
                // j-group consumed -> reload same slots with next c's frags
                if (cc < NC / 4 - 1) {
                    const u32x4* p = wb2i + (size_t)(c + 4) * 896;
                    #pragma unroll
                    for (int kk = 0; kk < 2; ++kk)
                        buf2A[j * 2 + kk] = p[((nb + j) * 2 + kk) * 64 + lane];
                }
            }
        }
    }

    // ---- write out partials (bf16): outP[cp][b][f] ----
    #pragma unroll
    for (int mt = 0; mt < 4; ++mt)
        #pragma unroll
        for (int j = 0; j < 4; ++j) {
            if (j < ne) {
                const int f = (nb + j) * 16 + col;
                if (f < NF) {
                    #pragma unroll
                    for (int r = 0; r < 4; ++r) {
                        const int b = mt * 16 + quad * 4 + r;
                        region[(cp * 64 + b) * 112 + f] = f2bf(Ot[mt][j][r]);
                    }
                }
            }
        }
    __syncthreads();

    // ---- final reduce + bias + relu, VECTORIZED: thread = (b, 8-f group) ----
    // 64 b x 13 groups (f 0..103; store masks f<100). 4x b128 reads each.
    for (int idx = tid; idx < BT * 13; idx += 512) {
        const int b = idx / 13, fg = idx % 13;
        const int f0 = fg * 8;
        float s[8] = {0.f, 0.f, 0.f, 0.f, 0.f, 0.f, 0.f, 0.f};
        #pragma unroll
        for (int p = 0; p < 4; ++p) {
            const u32x4 v = *(const u32x4*)&region[(p * 64 + b) * 112 + f0];
            const unsigned int vv[4] = {v.x, v.y, v.z, v.w};
            #pragma unroll
            for (int q = 0; q < 4; ++q) {
                s[q * 2 + 0] += bf2f((unsigned short)(vv[q] & 0xffffu));
                s[q * 2 + 1] += bf2f((unsigned short)(vv[q] >> 16));
            }
        }
        const float* bfp = b_final + i * NF + f0;
        float* op = out + ((size_t)(b0 + b) * NI + i) * NF + f0;
        const float4 bias0 = *(const float4*)bfp;   // f0..f0+3 (<=99 always)
        float4 o0;
        o0.x = fmaxf(s[0] + bias0.x, 0.f);
        o0.y = fmaxf(s[1] + bias0.y, 0.f);
        o0.z = fmaxf(s[2] + bias0.z, 0.f);
        o0.w = fmaxf(s[3] + bias0.w, 0.f);
        *(float4*)op = o0;
        if (fg < 12) {                              // f0+4..f0+7 < 100
            const float4 bias1 = *(const float4*)(bfp + 4);
            float4 o1;
            o1.x = fmaxf(s[4] + bias1.x, 0.f);
            o1.y = fmaxf(s[5] + bias1.y, 0.f);
            o1.z = fmaxf(s[6] + bias1.z, 0.f);
            o1.w = fmaxf(s[7] + bias1.w, 0.f);
            *(float4*)(op + 4) = o1;
        }
    }
}

extern "C" void kernel_launch(void* const* d_in, const int* in_sizes, int n_in,
                              void* d_out, int out_size, void* d_ws, size_t ws_size,
                              hipStream_t stream) {
    const float* x       = (const float*)d_in[0];  // (2048, 8, 100)
    const float* tk_mask = (const float*)d_in[1];  // (2048, 8, 40)
    const float* A       = (const float*)d_in[2];  // (8, 40, 100, 41)
    const float* Bp      = (const float*)d_in[3];  // (8, 40, 41, 40)
    const float* b_final = (const float*)d_in[4];  // (8, 100)
    float* out = (float*)d_out;                    // (2048, 8, 100)

    unsigned short* Wb1 = (unsigned short*)d_ws;
    unsigned short* Wb2 = Wb1 + (size_t)NI * NC * 768 * 8;

    build_w_kernel<<<NI * NC, 512, 0, stream>>>(A, Bp, Wb1, Wb2);
    fused_kernel<<<(BSZ / BT) * NI, 512, 0, stream>>>(x, tk_mask, b_final, Wb1, Wb2, out);
}